// Round 2
// baseline (333.976 us; speedup 1.0000x reference)
//
#include <hip/hip_runtime.h>
#include <hip/hip_bf16.h>
#include <stdint.h>

#define NN   4096
#define BB   4
#define CIN  128
#define COUT 64

typedef __attribute__((ext_vector_type(4))) float f32x4;
typedef __attribute__((ext_vector_type(8))) short s16x8;
typedef __attribute__((ext_vector_type(4))) int   i32x4;

// exp(sigmoid(u) - 0.5) via 2 x v_exp_f32 + 1 x v_rcp_f32
__device__ __forceinline__ float sig_exp(float u) {
    const float L = 1.4426950408889634f;      // log2(e)
    float e0 = __builtin_amdgcn_exp2f(-u * L);
    float sg = __builtin_amdgcn_rcpf(1.0f + e0);
    return __builtin_amdgcn_exp2f(__builtin_fmaf(sg, L, -0.7213475204444817f)); // -0.5*log2(e)
}

__device__ __forceinline__ short f2bf(float x) {
    unsigned u = __builtin_bit_cast(unsigned, x);
    return (short)((u + 0x8000u) >> 16);      // round-half-up bf16, fine for our ranges
}

// ---------------------------------------------------------------------------
// K0: zero the denom accumulator region (ws is poisoned 0xAA each launch)
__global__ void k_zero(float* __restrict__ p, int n) {
    int i = blockIdx.x * blockDim.x + threadIdx.x;
    if (i < n) p[i] = 0.0f;
}

// ---------------------------------------------------------------------------
// K1: h = node_rep @ proj_W^T + proj_b ; f1/f2 per-node scalars.
// One wave per (b,n) row; lane o = output channel.
__global__ __launch_bounds__(256) void k_proj(
    const float* __restrict__ node_rep, const int* __restrict__ node_type,
    const float* __restrict__ pW, const float* __restrict__ pb,
    const float* __restrict__ kW, const float* __restrict__ kb,
    const float* __restrict__ vW, const float* __restrict__ vb,
    float* __restrict__ h, float* __restrict__ f1, float* __restrict__ f2)
{
    int row = blockIdx.x * 4 + (threadIdx.x >> 6);   // 0 .. B*N-1
    int o   = threadIdx.x & 63;
    int n   = row & (NN - 1);

    const f32x4* xr = (const f32x4*)(node_rep + (size_t)row * CIN);
    const f32x4* wr = (const f32x4*)(pW + (size_t)o * CIN);
    float acc = pb[o];
    #pragma unroll
    for (int c = 0; c < CIN / 4; ++c) {
        f32x4 x = xr[c], w = wr[c];
        acc = fmaf(x[0], w[0], acc);
        acc = fmaf(x[1], w[1], acc);
        acc = fmaf(x[2], w[2], acc);
        acc = fmaf(x[3], w[3], acc);
    }
    h[(size_t)row * COUT + o] = acc;

    int t = node_type[n];
    float s1 = acc * kW[t * COUT + o];
    float s2 = acc * vW[t * COUT + o];
    #pragma unroll
    for (int off = 32; off; off >>= 1) {
        s1 += __shfl_xor(s1, off, 64);
        s2 += __shfl_xor(s2, off, 64);
    }
    if (o == 0) { f1[row] = s1 + kb[t]; f2[row] = s2 + vb[t]; }
}

// ---------------------------------------------------------------------------
// K2: denom[b][j] = sum_i exp(sigmoid(adj[i][j]*(f1[b][i]+f2[b][j])) - 0.5)
// grid (16 j-tiles of 256, 32 i-tiles of 128); 4 batches per thread; atomics.
__global__ __launch_bounds__(256) void k_denom(
    const float* __restrict__ adj, const float* __restrict__ f1,
    const float* __restrict__ f2, float* __restrict__ denom)
{
    int j  = blockIdx.x * 256 + threadIdx.x;
    int i0 = blockIdx.y * 128;
    float f2r[BB], acc[BB];
    #pragma unroll
    for (int b = 0; b < BB; ++b) { f2r[b] = f2[b * NN + j]; acc[b] = 0.0f; }
    for (int ii = 0; ii < 128; ++ii) {
        int i = i0 + ii;
        float a = adj[(size_t)i * NN + j];
        #pragma unroll
        for (int b = 0; b < BB; ++b) {
            float u = a * (f1[b * NN + i] + f2r[b]);
            acc[b] += sig_exp(u);
        }
    }
    #pragma unroll
    for (int b = 0; b < BB; ++b) atomicAdd(&denom[b * NN + j], acc[b]);
}

// ---------------------------------------------------------------------------
// K2.5: hsT[b][c][j] = bf16( h[b][j][c] / denom[b][j] )  (64x64 LDS transpose)
__global__ __launch_bounds__(256) void k_hst(
    const float* __restrict__ h, const float* __restrict__ denom,
    unsigned short* __restrict__ hsT)
{
    int b  = blockIdx.y;
    int j0 = blockIdx.x * 64;
    __shared__ float tile[64][65];
    int cx = threadIdx.x & 63;
    int ry = threadIdx.x >> 6;       // 0..3
    #pragma unroll
    for (int k = 0; k < 16; ++k) {
        int jl = k * 4 + ry;
        float d = denom[b * NN + j0 + jl];
        tile[jl][cx] = h[((size_t)b * NN + j0 + jl) * COUT + cx] / d;
    }
    __syncthreads();
    #pragma unroll
    for (int k = 0; k < 16; ++k) {
        int cl = k * 4 + ry;
        hsT[((size_t)b * COUT + cl) * NN + j0 + cx] = (unsigned short)f2bf(tile[cx][cl]);
    }
}

// ---------------------------------------------------------------------------
// K3: out[b][i][c] = sum_j exp(u[b][i][j]) * hs[b][j][c]
// Block: 16 i-rows, ALL 4 batches (adj tile read once). 512 threads = 8 waves
// splitting the j-range; LDS-reduce per batch at the end.
// MFMA 16x16x32 bf16; A tile (exp values) generated in registers with the
// same (lane,elem)->k map used for the B fragment load (k-permutation safe).
__global__ __launch_bounds__(512) void k_out(
    const float* __restrict__ adj, const float* __restrict__ f1,
    const float* __restrict__ f2, const unsigned short* __restrict__ hsT,
    float* __restrict__ out)
{
    int i0   = blockIdx.x * 16;
    int tid  = threadIdx.x;
    int wid  = tid >> 6;          // 0..7
    int lane = tid & 63;
    int lrow = lane & 15;
    int lgrp = lane >> 4;

    const float* arow = adj + (size_t)(i0 + lrow) * NN;
    float f1v[BB];
    #pragma unroll
    for (int b = 0; b < BB; ++b) f1v[b] = f1[b * NN + i0 + lrow];

    f32x4 acc[BB][4];
    #pragma unroll
    for (int b = 0; b < BB; ++b)
        #pragma unroll
        for (int r = 0; r < 4; ++r) acc[b][r] = (f32x4){0.f, 0.f, 0.f, 0.f};

    int jbeg = wid * (NN / 8);
    for (int js = 0; js < NN / 8; js += 32) {
        int jk = jbeg + js + lgrp * 8;
        f32x4 a0 = *(const f32x4*)(arow + jk);
        f32x4 a1 = *(const f32x4*)(arow + jk + 4);

        #pragma unroll
        for (int b = 0; b < BB; ++b) {
            const float* f2b = f2 + b * NN;
            f32x4 s0 = *(const f32x4*)(f2b + jk);
            f32x4 s1 = *(const f32x4*)(f2b + jk + 4);

            float e[8];
            #pragma unroll
            for (int q = 0; q < 4; ++q) {
                e[q]     = sig_exp(a0[q] * (f1v[b] + s0[q]));
                e[q + 4] = sig_exp(a1[q] * (f1v[b] + s1[q]));
            }
            s16x8 af;
            #pragma unroll
            for (int q = 0; q < 8; ++q) af[q] = f2bf(e[q]);

            const unsigned short* hsb = hsT + (size_t)b * COUT * NN;
            s16x8 b0 = __builtin_bit_cast(s16x8, *(const i32x4*)(hsb + (size_t)(0  + lrow) * NN + jk));
            s16x8 b1 = __builtin_bit_cast(s16x8, *(const i32x4*)(hsb + (size_t)(16 + lrow) * NN + jk));
            s16x8 b2 = __builtin_bit_cast(s16x8, *(const i32x4*)(hsb + (size_t)(32 + lrow) * NN + jk));
            s16x8 b3 = __builtin_bit_cast(s16x8, *(const i32x4*)(hsb + (size_t)(48 + lrow) * NN + jk));

            acc[b][0] = __builtin_amdgcn_mfma_f32_16x16x32_bf16(af, b0, acc[b][0], 0, 0, 0);
            acc[b][1] = __builtin_amdgcn_mfma_f32_16x16x32_bf16(af, b1, acc[b][1], 0, 0, 0);
            acc[b][2] = __builtin_amdgcn_mfma_f32_16x16x32_bf16(af, b2, acc[b][2], 0, 0, 0);
            acc[b][3] = __builtin_amdgcn_mfma_f32_16x16x32_bf16(af, b3, acc[b][3], 0, 0, 0);
        }
    }

    __shared__ float red[8][16][64];
    #pragma unroll
    for (int b = 0; b < BB; ++b) {
        if (b) __syncthreads();
        #pragma unroll
        for (int r = 0; r < 4; ++r) {
            red[wid][lgrp * 4 + r][ 0 + lrow] = acc[b][0][r];
            red[wid][lgrp * 4 + r][16 + lrow] = acc[b][1][r];
            red[wid][lgrp * 4 + r][32 + lrow] = acc[b][2][r];
            red[wid][lgrp * 4 + r][48 + lrow] = acc[b][3][r];
        }
        __syncthreads();

        int e2 = tid * 2;             // 512 threads x 2 floats = 16x64 tile
        int ii = e2 >> 6;
        int cc = e2 & 63;
        float sx = 0.f, sy = 0.f;
        #pragma unroll
        for (int w = 0; w < 8; ++w) {
            sx += red[w][ii][cc];
            sy += red[w][ii][cc + 1];
        }
        float* op = out + ((size_t)b * NN + i0 + ii) * COUT + cc;
        op[0] = sx; op[1] = sy;
    }
}

// ---------------------------------------------------------------------------
extern "C" void kernel_launch(void* const* d_in, const int* in_sizes, int n_in,
                              void* d_out, int out_size, void* d_ws, size_t ws_size,
                              hipStream_t stream)
{
    const float* node_rep = (const float*)d_in[0];
    const float* adj      = (const float*)d_in[1];
    const int*   ntype    = (const int*)  d_in[2];
    const float* pW       = (const float*)d_in[3];
    const float* pb       = (const float*)d_in[4];
    const float* kW       = (const float*)d_in[5];
    const float* kb       = (const float*)d_in[6];
    const float* vW       = (const float*)d_in[7];
    const float* vb       = (const float*)d_in[8];
    float* out = (float*)d_out;

    char* w = (char*)d_ws;
    float*          h     = (float*)(w);                       // 4  MiB
    float*          f1    = (float*)(w + 4194304);             // 64 KiB
    float*          f2    = (float*)(w + 4259840);             // 64 KiB
    float*          denom = (float*)(w + 4325376);             // 64 KiB
    unsigned short* hsT   = (unsigned short*)(w + 4390912);    // 2  MiB

    k_zero <<<64, 256, 0, stream>>>(denom, BB * NN);
    k_proj <<<BB * NN / 4, 256, 0, stream>>>(node_rep, ntype, pW, pb, kW, kb, vW, vb, h, f1, f2);
    k_denom<<<dim3(NN / 256, 32), 256, 0, stream>>>(adj, f1, f2, denom);
    k_hst  <<<dim3(NN / 64, BB), 256, 0, stream>>>(h, denom, hsT);
    k_out  <<<dim3(NN / 16), 512, 0, stream>>>(adj, f1, f2, hsT, out);
}

// Round 4
// 286.607 us; speedup vs baseline: 1.1653x; 1.1653x over previous
//
#include <hip/hip_runtime.h>
#include <hip/hip_bf16.h>
#include <stdint.h>

#define NN   4096
#define BB   4
#define CIN  128
#define COUT 64
#define JSPL 4          // j-splits in k_out
#define ITIL 32         // i-rows per k_denom block
#define NIT  (NN / ITIL)

typedef __attribute__((ext_vector_type(4))) float f32x4;
typedef __attribute__((ext_vector_type(8))) short s16x8;
typedef __attribute__((ext_vector_type(4))) int   i32x4;

// exp(sigmoid(u) - 0.5) via 2 x v_exp_f32 + 1 x v_rcp_f32
__device__ __forceinline__ float sig_exp(float u) {
    const float L = 1.4426950408889634f;      // log2(e)
    float e0 = __builtin_amdgcn_exp2f(-u * L);
    float sg = __builtin_amdgcn_rcpf(1.0f + e0);
    return __builtin_amdgcn_exp2f(__builtin_fmaf(sg, L, -0.7213475204444817f)); // -0.5*log2(e)
}

__device__ __forceinline__ short f2bf(float x) {
    unsigned u = __builtin_bit_cast(unsigned, x);
    return (short)((u + 0x8000u) >> 16);      // round-half-up bf16
}

// ---------------------------------------------------------------------------
// K1: h = node_rep @ proj_W^T + proj_b ; f1/f2 per-node scalars.
// One wave per (b,n) row; lane o = output channel. 4 accumulators for ILP.
__global__ __launch_bounds__(256) void k_proj(
    const float* __restrict__ node_rep, const int* __restrict__ node_type,
    const float* __restrict__ pW, const float* __restrict__ pb,
    const float* __restrict__ kW, const float* __restrict__ kb,
    const float* __restrict__ vW, const float* __restrict__ vb,
    float* __restrict__ h, float* __restrict__ f1, float* __restrict__ f2)
{
    int row = blockIdx.x * 4 + (threadIdx.x >> 6);   // 0 .. B*N-1
    int o   = threadIdx.x & 63;
    int n   = row & (NN - 1);

    const f32x4* xr = (const f32x4*)(node_rep + (size_t)row * CIN);
    const f32x4* wr = (const f32x4*)(pW + (size_t)o * CIN);
    float a0 = pb[o], a1 = 0.f, a2 = 0.f, a3 = 0.f;
    #pragma unroll
    for (int c = 0; c < CIN / 4; ++c) {
        f32x4 x = xr[c], w = wr[c];
        a0 = fmaf(x[0], w[0], a0);
        a1 = fmaf(x[1], w[1], a1);
        a2 = fmaf(x[2], w[2], a2);
        a3 = fmaf(x[3], w[3], a3);
    }
    float acc = (a0 + a1) + (a2 + a3);
    h[(size_t)row * COUT + o] = acc;

    int t = node_type[n];
    float s1 = acc * kW[t * COUT + o];
    float s2 = acc * vW[t * COUT + o];
    #pragma unroll
    for (int off = 32; off; off >>= 1) {
        s1 += __shfl_xor(s1, off, 64);
        s2 += __shfl_xor(s2, off, 64);
    }
    if (o == 0) { f1[row] = s1 + kb[t]; f2[row] = s2 + vb[t]; }
}

// ---------------------------------------------------------------------------
// K2: partial denom, no atomics.  pd[(it*BB+b)*NN + j] = sum over 32 i rows.
// grid (NN/256, NIT) = (16, 128) = 2048 blocks -> full occupancy.
__global__ __launch_bounds__(256) void k_denom(
    const float* __restrict__ adj, const float* __restrict__ f1,
    const float* __restrict__ f2, float* __restrict__ pd)
{
    int j  = blockIdx.x * 256 + threadIdx.x;
    int it = blockIdx.y;
    int i0 = it * ITIL;
    float f2r[BB], acc[BB];
    #pragma unroll
    for (int b = 0; b < BB; ++b) { f2r[b] = f2[b * NN + j]; acc[b] = 0.0f; }
    #pragma unroll 2
    for (int ii = 0; ii < ITIL; ii += 2) {
        float a0 = adj[(size_t)(i0 + ii)     * NN + j];
        float a1 = adj[(size_t)(i0 + ii + 1) * NN + j];
        #pragma unroll
        for (int b = 0; b < BB; ++b) {
            float fa = f1[b * NN + i0 + ii];
            float fb = f1[b * NN + i0 + ii + 1];
            acc[b] += sig_exp(a0 * (fa + f2r[b])) + sig_exp(a1 * (fb + f2r[b]));
        }
    }
    #pragma unroll
    for (int b = 0; b < BB; ++b) pd[(size_t)(it * BB + b) * NN + j] = acc[b];
}

// ---------------------------------------------------------------------------
// K2.1: rden[b][j] = 1 / sum_it pd[it][b][j]
__global__ __launch_bounds__(256) void k_dred(
    const float* __restrict__ pd, float* __restrict__ rden)
{
    int gid = blockIdx.x * 256 + threadIdx.x;      // 0 .. BB*NN-1
    float s = 0.0f;
    for (int it = 0; it < NIT; ++it) s += pd[(size_t)it * BB * NN + gid];
    rden[gid] = 1.0f / s;
}

// ---------------------------------------------------------------------------
// K2.5: hsT[b][c][j] = bf16( h[b][j][c] * rden[b][j] )  (64x64 LDS transpose)
__global__ __launch_bounds__(256) void k_hst(
    const float* __restrict__ h, const float* __restrict__ rden,
    unsigned short* __restrict__ hsT)
{
    int b  = blockIdx.y;
    int j0 = blockIdx.x * 64;
    __shared__ float tile[64][65];
    int cx = threadIdx.x & 63;
    int ry = threadIdx.x >> 6;       // 0..3
    #pragma unroll
    for (int k = 0; k < 16; ++k) {
        int jl = k * 4 + ry;
        float d = rden[b * NN + j0 + jl];
        tile[jl][cx] = h[((size_t)b * NN + j0 + jl) * COUT + cx] * d;
    }
    __syncthreads();
    #pragma unroll
    for (int k = 0; k < 16; ++k) {
        int cl = k * 4 + ry;
        hsT[((size_t)b * COUT + cl) * NN + j0 + cx] = (unsigned short)f2bf(tile[cx][cl]);
    }
}

// ---------------------------------------------------------------------------
// K3: partial out over a quarter of the j-range.
// grid (NN/16, JSPL) = 1024 blocks x 512 threads.  8 waves split the quarter.
// pout[(js*BB + b)][i][c] partials in ws; reduced by k_ored.
__global__ __launch_bounds__(512) void k_out(
    const float* __restrict__ adj, const float* __restrict__ f1,
    const float* __restrict__ f2, const unsigned short* __restrict__ hsT,
    float* __restrict__ pout)
{
    int i0   = blockIdx.x * 16;
    int jsp  = blockIdx.y;
    int tid  = threadIdx.x;
    int wid  = tid >> 6;          // 0..7
    int lane = tid & 63;
    int lrow = lane & 15;
    int lgrp = lane >> 4;

    const float* arow = adj + (size_t)(i0 + lrow) * NN;
    float f1v[BB];
    #pragma unroll
    for (int b = 0; b < BB; ++b) f1v[b] = f1[b * NN + i0 + lrow];

    f32x4 acc[BB][4];
    #pragma unroll
    for (int b = 0; b < BB; ++b)
        #pragma unroll
        for (int r = 0; r < 4; ++r) acc[b][r] = (f32x4){0.f, 0.f, 0.f, 0.f};

    int jbeg = jsp * (NN / JSPL) + wid * (NN / JSPL / 8);
    for (int js = 0; js < NN / JSPL / 8; js += 32) {
        int jk = jbeg + js + lgrp * 8;
        f32x4 a0 = *(const f32x4*)(arow + jk);
        f32x4 a1 = *(const f32x4*)(arow + jk + 4);

        #pragma unroll
        for (int b = 0; b < BB; ++b) {
            const float* f2b = f2 + b * NN;
            f32x4 s0 = *(const f32x4*)(f2b + jk);
            f32x4 s1 = *(const f32x4*)(f2b + jk + 4);

            float e[8];
            #pragma unroll
            for (int q = 0; q < 4; ++q) {
                e[q]     = sig_exp(a0[q] * (f1v[b] + s0[q]));
                e[q + 4] = sig_exp(a1[q] * (f1v[b] + s1[q]));
            }
            s16x8 af;
            #pragma unroll
            for (int q = 0; q < 8; ++q) af[q] = f2bf(e[q]);

            const unsigned short* hsb = hsT + (size_t)b * COUT * NN;
            s16x8 b0 = __builtin_bit_cast(s16x8, *(const i32x4*)(hsb + (size_t)(0  + lrow) * NN + jk));
            s16x8 b1 = __builtin_bit_cast(s16x8, *(const i32x4*)(hsb + (size_t)(16 + lrow) * NN + jk));
            s16x8 b2 = __builtin_bit_cast(s16x8, *(const i32x4*)(hsb + (size_t)(32 + lrow) * NN + jk));
            s16x8 b3 = __builtin_bit_cast(s16x8, *(const i32x4*)(hsb + (size_t)(48 + lrow) * NN + jk));

            acc[b][0] = __builtin_amdgcn_mfma_f32_16x16x32_bf16(af, b0, acc[b][0], 0, 0, 0);
            acc[b][1] = __builtin_amdgcn_mfma_f32_16x16x32_bf16(af, b1, acc[b][1], 0, 0, 0);
            acc[b][2] = __builtin_amdgcn_mfma_f32_16x16x32_bf16(af, b2, acc[b][2], 0, 0, 0);
            acc[b][3] = __builtin_amdgcn_mfma_f32_16x16x32_bf16(af, b3, acc[b][3], 0, 0, 0);
        }
    }

    __shared__ float red[8][16][64];
    #pragma unroll
    for (int b = 0; b < BB; ++b) {
        if (b) __syncthreads();
        #pragma unroll
        for (int r = 0; r < 4; ++r) {
            red[wid][lgrp * 4 + r][ 0 + lrow] = acc[b][0][r];
            red[wid][lgrp * 4 + r][16 + lrow] = acc[b][1][r];
            red[wid][lgrp * 4 + r][32 + lrow] = acc[b][2][r];
            red[wid][lgrp * 4 + r][48 + lrow] = acc[b][3][r];
        }
        __syncthreads();

        int e2 = tid * 2;             // 512 threads x 2 floats = 16x64 tile
        int ii = e2 >> 6;
        int cc = e2 & 63;
        float sx = 0.f, sy = 0.f;
        #pragma unroll
        for (int w = 0; w < 8; ++w) {
            sx += red[w][ii][cc];
            sy += red[w][ii][cc + 1];
        }
        float* op = pout + ((size_t)(jsp * BB + b) * NN + i0 + ii) * COUT + cc;
        op[0] = sx; op[1] = sy;
    }
}

// ---------------------------------------------------------------------------
// K4: out = sum over JSPL partials.  1024 blocks x 256 threads x f32x4.
__global__ __launch_bounds__(256) void k_ored(
    const float* __restrict__ pout, float* __restrict__ out)
{
    size_t e = ((size_t)blockIdx.x * 256 + threadIdx.x) * 4;
    f32x4 s = *(const f32x4*)(pout + e);
    #pragma unroll
    for (int sp = 1; sp < JSPL; ++sp)
        s += *(const f32x4*)(pout + (size_t)sp * BB * NN * COUT + e);
    *(f32x4*)(out + e) = s;
}

// ---------------------------------------------------------------------------
extern "C" void kernel_launch(void* const* d_in, const int* in_sizes, int n_in,
                              void* d_out, int out_size, void* d_ws, size_t ws_size,
                              hipStream_t stream)
{
    const float* node_rep = (const float*)d_in[0];
    const float* adj      = (const float*)d_in[1];
    const int*   ntype    = (const int*)  d_in[2];
    const float* pW       = (const float*)d_in[3];
    const float* pb       = (const float*)d_in[4];
    const float* kW       = (const float*)d_in[5];
    const float* kb       = (const float*)d_in[6];
    const float* vW       = (const float*)d_in[7];
    const float* vb       = (const float*)d_in[8];
    float* out = (float*)d_out;

    char* w = (char*)d_ws;
    float*          h     = (float*)(w);                       // 4 MiB
    float*          f1    = (float*)(w + 4194304);             // 64 KiB
    float*          f2    = (float*)(w + 4259840);             // 64 KiB
    float*          rden  = (float*)(w + 4325376);             // 64 KiB
    unsigned short* hsT   = (unsigned short*)(w + 4390912);    // 2 MiB
    float*          pd    = (float*)(w + 6488064);             // 8 MiB (NIT*BB*NN)
    float*          pout  = (float*)(w + 14876672);            // 16 MiB (JSPL*BB*NN*COUT)

    k_proj <<<BB * NN / 4, 256, 0, stream>>>(node_rep, ntype, pW, pb, kW, kb, vW, vb, h, f1, f2);
    k_denom<<<dim3(NN / 256, NIT), 256, 0, stream>>>(adj, f1, f2, pd);
    k_dred <<<BB * NN / 256, 256, 0, stream>>>(pd, rden);
    k_hst  <<<dim3(NN / 64, BB), 256, 0, stream>>>(h, rden, hsT);
    k_out  <<<dim3(NN / 16, JSPL), 512, 0, stream>>>(adj, f1, f2, hsT, pout);
    k_ored <<<BB * NN * COUT / 1024, 256, 0, stream>>>(pout, out);
}